// Round 5
// baseline (331.507 us; speedup 1.0000x reference)
//
#include <hip/hip_runtime.h>
#include <math.h>

#define DMODEL 384
#define DIN 768
#define NST 16
#define DTR 48
#define BSZ 8
#define LSEQ 1024
#define NROWS (BSZ*LSEQ)      // 8192
#define XPO_W (DTR + 2*NST)   // 80
#define CL 64                 // chunk length for scan
#define NC (LSEQ/CL)          // 16 chunks

typedef __attribute__((ext_vector_type(8))) short bf16x8;
typedef __attribute__((ext_vector_type(4))) float f32x4;

__device__ __forceinline__ unsigned short f2bf(float x) {
  unsigned int u = __float_as_uint(x);
  unsigned int r = u + 0x7fffu + ((u >> 16) & 1u);
  return (unsigned short)(r >> 16);
}
__device__ __forceinline__ float bf2f(unsigned short h) {
  return __uint_as_float(((unsigned int)h) << 16);
}

__device__ __forceinline__ void gll16(const void* g, void* l) {
  __builtin_amdgcn_global_load_lds(
      (const __attribute__((address_space(1))) void*)g,
      (__attribute__((address_space(3))) void*)l, 16, 0, 0);
}

// ---------------- LayerNorm: 4 rows per 256-thread block, emits hi/lo bf16 ----------------
__global__ __launch_bounds__(256) void ln_kernel(const float* __restrict__ x,
    const float* __restrict__ g, const float* __restrict__ b,
    unsigned short* __restrict__ xh, unsigned short* __restrict__ xl) {
  int row = blockIdx.x * 4 + (threadIdx.x >> 6);
  int lane = threadIdx.x & 63;
  const float* xr = x + (size_t)row * DMODEL;
  float v[6];
  float s = 0.f, ss = 0.f;
#pragma unroll
  for (int i = 0; i < 6; ++i) { v[i] = xr[lane + i*64]; s += v[i]; ss += v[i]*v[i]; }
#pragma unroll
  for (int off = 32; off; off >>= 1) { s += __shfl_xor(s, off); ss += __shfl_xor(ss, off); }
  float mu = s * (1.f / DMODEL);
  float var = ss * (1.f / DMODEL) - mu * mu;
  float inv = rsqrtf(var + 1e-5f);
#pragma unroll
  for (int i = 0; i < 6; ++i) {
    int c = lane + i*64;
    float o = (v[i] - mu) * inv * g[c] + b[c];
    unsigned short hv = f2bf(o);
    xh[(size_t)row*DMODEL + c] = hv;
    xl[(size_t)row*DMODEL + c] = f2bf(o - bf2f(hv));
  }
}

// ---------------- single fused weight split+pad kernel ----------------
__device__ __forceinline__ void split_one(const float* src, int ldsrc, int R, int C,
    unsigned short* dh, unsigned short* dl, int Cpad, int i) {
  int r = i / Cpad, c = i - r * Cpad;
  float v = (r < R && c < C) ? src[(size_t)r*ldsrc + c] : 0.f;
  unsigned short hv = f2bf(v);
  dh[i] = hv;
  dl[i] = f2bf(v - bf2f(hv));
}
#define N_INW (1536*384)
#define N_XW  (128*768)
#define N_DTW (768*64)
#define N_OW  (384*768)
__global__ __launch_bounds__(256) void split_weights(
    const float* __restrict__ inw, const float* __restrict__ xw,
    const float* __restrict__ dtw, const float* __restrict__ ow,
    unsigned short* inw_h, unsigned short* inw_l,
    unsigned short* xw_h, unsigned short* xw_l,
    unsigned short* dtw_h, unsigned short* dtw_l,
    unsigned short* ow_h, unsigned short* ow_l) {
  int i = blockIdx.x * 256 + threadIdx.x;
  if (i < N_INW) { split_one(inw, 384, 1536, 384, inw_h, inw_l, 384, i); return; }
  i -= N_INW;
  if (i < N_XW)  { split_one(xw, 768, 80, 768, xw_h, xw_l, 768, i); return; }
  i -= N_XW;
  if (i < N_DTW) { split_one(dtw, 48, 768, 48, dtw_h, dtw_l, 64, i); return; }
  i -= N_DTW;
  if (i < N_OW)  { split_one(ow, 768, 384, 768, ow_h, ow_l, 768, i); return; }
}

// ---------------- virtual-K split-bf16 MFMA GEMM, 3-deep counted-vmcnt pipeline ------------
// C = A * B^T with A = Ah+Al, B = Bh+Bl, computed as one GEMM over K' = 3K:
// k-ranges [0,K):Ah*Bh, [K,2K):Al*Bh, [2K,3K):Ah*Bl.
// BM=256, BN=128, BK=32, 512 threads = 8 waves (4m x 2n), wave tile 64x64.
// grid = (N/128, M/256, S); split-K' via blockIdx.z: each split does T ksteps.
// EPI: 0 plain store (C += z*strideS), 2 bias+softplus, 3 residual add
template<int EPI>
__global__ __launch_bounds__(512, 4) void gemm3(
    const unsigned short* __restrict__ Ah, const unsigned short* __restrict__ Al, int lda,
    const unsigned short* __restrict__ Bh, const unsigned short* __restrict__ Bl, int ldb,
    float* __restrict__ C, int ldc, size_t strideS,
    const float* __restrict__ bias, const float* __restrict__ res,
    int K, int T) {
  // buffer: A cells [kg(4)][row(256)] then B cells [kg(4)][row(128)], 16B/cell
  __shared__ unsigned short lds[3][12288];
  int tid = threadIdx.x;
  int lane = tid & 63, wid = tid >> 6;
  int wm = wid >> 1, wn = wid & 1;

  // bijective XCD swizzle over (x,y); all grids have nwg % 8 == 0
  unsigned nwg = gridDim.x * gridDim.y;
  unsigned bid = blockIdx.y * gridDim.x + blockIdx.x;
  unsigned cpx = nwg >> 3;
  unsigned sw = (bid & 7) * cpx + (bid >> 3);
  unsigned bx = sw % gridDim.x, by = sw / gridDim.x;
  int m0 = by * 256, n0 = bx * 128;
  C += (size_t)blockIdx.z * strideS;
  int kbase = blockIdx.z * T;

  // staging geometry: 1536 cells (1024 A + 512 B), 3 gll16 per thread per kstep
  int c0 = wid*64 + lane;              // A cells 0..511
  int c1 = 512 + c0;                   // A cells 512..1023
  size_t ga0 = (size_t)(m0 + (c0 & 255)) * lda + (c0 >> 8) * 8;
  size_t ga1 = (size_t)(m0 + (c1 & 255)) * lda + (c1 >> 8) * 8;
  size_t gb0 = (size_t)(n0 + (c0 & 127)) * ldb + (c0 >> 7) * 8;
  int d0 = (wid*64) * 8;               // LDS ushort offsets (wave-uniform bases)
  int d1 = (512 + wid*64) * 8;
  int d2 = (1024 + wid*64) * 8;

#define STAGE(bf, tt) do { \
    int kvt = (kbase + (tt)) << 5; \
    int term = (kvt >= 2*K) ? 2 : ((kvt >= K) ? 1 : 0); \
    int kk = kvt - term * K; \
    const unsigned short* As = (term == 1) ? Al : Ah; \
    const unsigned short* Bs = (term == 2) ? Bl : Bh; \
    gll16(As + ga0 + kk, &lds[bf][d0]); \
    gll16(As + ga1 + kk, &lds[bf][d1]); \
    gll16(Bs + gb0 + kk, &lds[bf][d2]); \
  } while (0)

  f32x4 acc[4][4];
#pragma unroll
  for (int i = 0; i < 4; ++i)
#pragma unroll
    for (int j = 0; j < 4; ++j) acc[i][j] = (f32x4){0.f, 0.f, 0.f, 0.f};

  int kgl = lane >> 4, rl = lane & 15;

  STAGE(0, 0);
  if (T > 1) STAGE(1, 1);

  int cur = 0;
  for (int t = 0; t < T; ++t) {
    if (t + 2 < T) {
      int nb = (cur == 0) ? 2 : cur - 1;   // (cur+2)%3
      STAGE(nb, t + 2);
      asm volatile("s_waitcnt vmcnt(6)" ::: "memory");
    } else if (t + 1 < T) {
      asm volatile("s_waitcnt vmcnt(3)" ::: "memory");
    } else {
      asm volatile("s_waitcnt vmcnt(0)" ::: "memory");
    }
    __builtin_amdgcn_s_barrier();      // buf[cur] fully staged

    const unsigned short* Lp = lds[cur];
    bf16x8 af[4], bf_[4];
#pragma unroll
    for (int mi = 0; mi < 4; ++mi)
      af[mi] = *reinterpret_cast<const bf16x8*>(&Lp[(kgl*256 + wm*64 + mi*16 + rl) * 8]);
#pragma unroll
    for (int ni = 0; ni < 4; ++ni)
      bf_[ni] = *reinterpret_cast<const bf16x8*>(&Lp[8192 + (kgl*128 + wn*64 + ni*16 + rl) * 8]);
    asm volatile("s_waitcnt lgkmcnt(0)" ::: "memory");
    __builtin_amdgcn_sched_barrier(0);
    __builtin_amdgcn_s_barrier();      // all waves done reading buf[cur]; safe to overwrite

#pragma unroll
    for (int mi = 0; mi < 4; ++mi)
#pragma unroll
      for (int ni = 0; ni < 4; ++ni)
        acc[mi][ni] = __builtin_amdgcn_mfma_f32_16x16x32_bf16(af[mi], bf_[ni], acc[mi][ni], 0, 0, 0);

    cur = (cur == 2) ? 0 : cur + 1;
  }
#undef STAGE

  // epilogue: C/D frag layout col=lane&15, row=(lane>>4)*4+j
#pragma unroll
  for (int mi = 0; mi < 4; ++mi)
#pragma unroll
    for (int ni = 0; ni < 4; ++ni)
#pragma unroll
      for (int j = 0; j < 4; ++j) {
        int m = m0 + wm*64 + mi*16 + (lane>>4)*4 + j;
        int n = n0 + wn*64 + ni*16 + (lane&15);
        float v = acc[mi][ni][j];
        if (EPI == 0) {
          C[(size_t)m*ldc + n] = v;
        } else if (EPI == 2) {
          v += bias[n];
          v = (v > 20.f) ? v : log1pf(__expf(v));
          C[(size_t)m*ldc + n] = v;
        } else if (EPI == 3) {
          C[(size_t)m*ldc + n] = v + res[(size_t)m*ldc + n];
        }
      }
}

// ---------------- x_proj split-K reduce: sum 6 partials -> xpo fp32 + dlow hi/lo ----------
__global__ __launch_bounds__(256) void reduce_xproj(
    const float* __restrict__ P, float* __restrict__ xpo,
    unsigned short* __restrict__ dh, unsigned short* __restrict__ dl) {
  int idx = blockIdx.x * 256 + threadIdx.x;   // NROWS*128
  int m = idx >> 7, n = idx & 127;
  float v = 0.f;
#pragma unroll
  for (int s = 0; s < 6; ++s) v += P[(size_t)s * NROWS * 128 + idx];
  if (n < XPO_W) xpo[(size_t)m * XPO_W + n] = v;
  if (n < 64) {   // cols 48..63 are garbage x dtw-zeros -> harmless
    unsigned short hv = f2bf(v);
    dh[(size_t)m*64 + n] = hv;
    dl[(size_t)m*64 + n] = f2bf(v - bf2f(hv));
  }
}

// ---------------- causal depthwise conv (width 4) + SiLU, emits u hi/lo ----------------
__global__ __launch_bounds__(256) void conv_silu_kernel(
    const float* __restrict__ xz, const float* __restrict__ w,
    const float* __restrict__ cb,
    unsigned short* __restrict__ uh, unsigned short* __restrict__ ul) {
  int r = blockIdx.x / 3;                       // row (b*L + l)
  int d = (blockIdx.x % 3) * 256 + threadIdx.x; // channel
  int l = r & (LSEQ - 1);
  size_t idx = (size_t)r * DIN + d;
  float acc = cb[d];
#pragma unroll
  for (int j = 0; j < 4; ++j) {
    int li = l - 3 + j;
    if (li >= 0)
      acc = fmaf(xz[(size_t)(r - l + li) * (2*DIN) + d], w[d*4 + j], acc);
  }
  float s = acc / (1.f + __expf(-acc));   // silu
  unsigned short hv = f2bf(s);
  uh[idx] = hv;
  ul[idx] = f2bf(s - bf2f(hv));
}

// ---------------- chunked selective scan ----------------
__global__ __launch_bounds__(256) void scan_pass1(
    const float* __restrict__ delta,
    const unsigned short* __restrict__ uh, const unsigned short* __restrict__ ul,
    const float* __restrict__ xpo, const float* __restrict__ A_log,
    float* __restrict__ carryA, float* __restrict__ carryH) {
  int d = blockIdx.x * 256 + threadIdx.x;
  int c = blockIdx.y, b = blockIdx.z;
  float A[16];
  {
    const float4* al = reinterpret_cast<const float4*>(A_log + (size_t)d * NST);
#pragma unroll
    for (int i = 0; i < 4; ++i) {
      float4 t = al[i];
      A[4*i+0] = -__expf(t.x); A[4*i+1] = -__expf(t.y);
      A[4*i+2] = -__expf(t.z); A[4*i+3] = -__expf(t.w);
    }
  }
  float h[16], ap[16];
#pragma unroll
  for (int n = 0; n < 16; ++n) { h[n] = 0.f; ap[n] = 1.f; }
  const float* dp = delta + ((size_t)b*LSEQ + c*CL) * DIN + d;
  const unsigned short* uhp = uh + ((size_t)b*LSEQ + c*CL) * DIN + d;
  const unsigned short* ulp = ul + ((size_t)b*LSEQ + c*CL) * DIN + d;
  const float* bp = xpo   + ((size_t)b*LSEQ + c*CL) * XPO_W + DTR;
  for (int l = 0; l < CL; ++l) {
    float dv = dp[(size_t)l*DIN];
    float uv = bf2f(uhp[(size_t)l*DIN]) + bf2f(ulp[(size_t)l*DIN]);
    float du = dv * uv;
    float Bv[16];
    {
      const float4* b4 = reinterpret_cast<const float4*>(bp + (size_t)l*XPO_W);
#pragma unroll
      for (int i = 0; i < 4; ++i) {
        float4 t = b4[i];
        Bv[4*i+0] = t.x; Bv[4*i+1] = t.y; Bv[4*i+2] = t.z; Bv[4*i+3] = t.w;
      }
    }
#pragma unroll
    for (int n = 0; n < 16; ++n) {
      float a = __expf(dv * A[n]);
      ap[n] *= a;
      h[n] = fmaf(a, h[n], du * Bv[n]);
    }
  }
  size_t ci = (((size_t)b*NC + c) * DIN + d) * NST;
  float4* ca = reinterpret_cast<float4*>(carryA + ci);
  float4* ch = reinterpret_cast<float4*>(carryH + ci);
#pragma unroll
  for (int i = 0; i < 4; ++i) {
    ca[i] = make_float4(ap[4*i], ap[4*i+1], ap[4*i+2], ap[4*i+3]);
    ch[i] = make_float4(h[4*i],  h[4*i+1],  h[4*i+2],  h[4*i+3]);
  }
}

__global__ __launch_bounds__(256) void scan_mid(
    const float* __restrict__ carryA, float* __restrict__ carryH) {
  int idx = blockIdx.x * 256 + threadIdx.x;
  int b = idx / (DIN*NST);
  int rem = idx - b * DIN*NST;
  float h = 0.f;
#pragma unroll
  for (int c = 0; c < NC; ++c) {
    size_t i = ((size_t)b*NC + c) * (DIN*NST) + rem;
    float a = carryA[i];
    float e = carryH[i];
    carryH[i] = h;
    h = fmaf(a, h, e);
  }
}

__global__ __launch_bounds__(256) void scan_pass2(
    const float* __restrict__ delta,
    const unsigned short* __restrict__ uh, const unsigned short* __restrict__ ul,
    const float* __restrict__ xpo, const float* __restrict__ xz,
    const float* __restrict__ A_log, const float* __restrict__ Dp,
    const float* __restrict__ carryH,
    unsigned short* __restrict__ yh, unsigned short* __restrict__ yl) {
  int d = blockIdx.x * 256 + threadIdx.x;
  int c = blockIdx.y, b = blockIdx.z;
  float A[16];
  {
    const float4* al = reinterpret_cast<const float4*>(A_log + (size_t)d * NST);
#pragma unroll
    for (int i = 0; i < 4; ++i) {
      float4 t = al[i];
      A[4*i+0] = -__expf(t.x); A[4*i+1] = -__expf(t.y);
      A[4*i+2] = -__expf(t.z); A[4*i+3] = -__expf(t.w);
    }
  }
  float h[16];
  size_t ci = (((size_t)b*NC + c) * DIN + d) * NST;
  {
    const float4* ch = reinterpret_cast<const float4*>(carryH + ci);
#pragma unroll
    for (int i = 0; i < 4; ++i) {
      float4 t = ch[i];
      h[4*i+0] = t.x; h[4*i+1] = t.y; h[4*i+2] = t.z; h[4*i+3] = t.w;
    }
  }
  float Dd = Dp[d];
  const float* dp = delta + ((size_t)b*LSEQ + c*CL) * DIN + d;
  const unsigned short* uhp = uh + ((size_t)b*LSEQ + c*CL) * DIN + d;
  const unsigned short* ulp = ul + ((size_t)b*LSEQ + c*CL) * DIN + d;
  const float* bp = xpo   + ((size_t)b*LSEQ + c*CL) * XPO_W + DTR;
  const float* zp = xz    + ((size_t)b*LSEQ + c*CL) * (2*DIN) + DIN + d;
  size_t yi0 = ((size_t)b*LSEQ + c*CL) * DIN + d;
  for (int l = 0; l < CL; ++l) {
    float dv = dp[(size_t)l*DIN];
    float uv = bf2f(uhp[(size_t)l*DIN]) + bf2f(ulp[(size_t)l*DIN]);
    float du = dv * uv;
    float Bv[16], Cv[16];
    {
      const float4* b4 = reinterpret_cast<const float4*>(bp + (size_t)l*XPO_W);
#pragma unroll
      for (int i = 0; i < 4; ++i) {
        float4 t = b4[i];
        Bv[4*i+0] = t.x; Bv[4*i+1] = t.y; Bv[4*i+2] = t.z; Bv[4*i+3] = t.w;
        float4 tc = b4[i+4];
        Cv[4*i+0] = tc.x; Cv[4*i+1] = tc.y; Cv[4*i+2] = tc.z; Cv[4*i+3] = tc.w;
      }
    }
    float p = 0.f;
#pragma unroll
    for (int n = 0; n < 16; ++n) {
      float a = __expf(dv * A[n]);
      h[n] = fmaf(a, h[n], du * Bv[n]);
      p = fmaf(h[n], Cv[n], p);
    }
    float z = zp[(size_t)l*(2*DIN)];
    float sz = z / (1.f + __expf(-z));
    float yv = fmaf(uv, Dd, p) * sz;
    unsigned short hv = f2bf(yv);
    yh[yi0 + (size_t)l*DIN] = hv;
    yl[yi0 + (size_t)l*DIN] = f2bf(yv - bf2f(hv));
  }
}

extern "C" void kernel_launch(void* const* d_in, const int* in_sizes, int n_in,
                              void* d_out, int out_size, void* d_ws, size_t ws_size,
                              hipStream_t stream) {
  const float* x          = (const float*)d_in[0];
  const float* ln_g       = (const float*)d_in[1];
  const float* ln_b       = (const float*)d_in[2];
  const float* in_proj_w  = (const float*)d_in[3];   // (1536,384)
  const float* conv_w     = (const float*)d_in[4];   // (768,1,4)
  const float* conv_b     = (const float*)d_in[5];
  const float* x_proj_w   = (const float*)d_in[6];   // (80,768)
  const float* dt_proj_w  = (const float*)d_in[7];   // (768,48)
  const float* dt_proj_b  = (const float*)d_in[8];
  const float* A_log      = (const float*)d_in[9];   // (768,16)
  const float* D_param    = (const float*)d_in[10];
  const float* out_proj_w = (const float*)d_in[11];  // (384,768)

  char* w = (char*)d_ws;
  // region1 (12.58MB): xn hi/lo -> dlow hi/lo -> carryA/H (lifetimes disjoint)
  unsigned short* xn_h  = (unsigned short*)w;
  unsigned short* xn_l  = xn_h + (size_t)NROWS*DMODEL;
  unsigned short* dlow_h = (unsigned short*)w;
  unsigned short* dlow_l = dlow_h + (size_t)NROWS*64;
  float* carryA = (float*)w;
  float* carryH = carryA + (size_t)BSZ*NC*DIN*NST;
  char* p = w + (size_t)NROWS*DMODEL*4;               // 12.58MB
  float* xz = (float*)p;              p += (size_t)NROWS*2*DIN*4;   // 50.33MB
  unsigned short* u_h = (unsigned short*)p;
  unsigned short* u_l = u_h + (size_t)NROWS*DIN;      p += (size_t)NROWS*DIN*4; // 25.17MB
  float* xpo = (float*)p;             p += (size_t)NROWS*XPO_W*4;   // 2.62MB
  float* delta = (float*)p;           p += (size_t)NROWS*DIN*4;     // 25.17MB
  // weight splits for in_proj/x_proj live in the (not yet written) delta region
  unsigned short* inw_h = (unsigned short*)delta;
  unsigned short* inw_l = inw_h + (size_t)1536*384;
  unsigned short* xw_h  = inw_l + (size_t)1536*384;
  unsigned short* xw_l  = xw_h + (size_t)128*768;
  // y2 region: x_proj split-K partials (6 x 8192 x 128 fp32 = exactly 25.17MB) pre-scan
  unsigned short* y2_h = (unsigned short*)p;
  unsigned short* y2_l = y2_h + (size_t)NROWS*DIN;
  float* xpart = (float*)p;           p += (size_t)NROWS*DIN*4;     // 25.17MB
  unsigned short* dtw_h = (unsigned short*)p;
  unsigned short* dtw_l = dtw_h + (size_t)768*64;
  unsigned short* ow_h  = dtw_l + (size_t)768*64;
  unsigned short* ow_l  = ow_h + (size_t)384*768;

  // 0. split all weights in one launch (pads: x_proj rows 80->128, dt_proj cols 48->64)
  split_weights<<<(N_INW+N_XW+N_DTW+N_OW)/256, 256, 0, stream>>>(
      in_proj_w, x_proj_w, dt_proj_w, out_proj_w,
      inw_h, inw_l, xw_h, xw_l, dtw_h, dtw_l, ow_h, ow_l);

  // 1. LayerNorm -> xn hi/lo
  ln_kernel<<<NROWS/4, 256, 0, stream>>>(x, ln_g, ln_b, xn_h, xn_l);

  // 2. in_proj: xz = xn @ in_proj_w^T   (M=8192, N=1536, K=384, K'=1152, T=36)
  gemm3<0><<<dim3(12, 32, 1), 512, 0, stream>>>(xn_h, xn_l, DMODEL, inw_h, inw_l, DMODEL,
      xz, 2*DIN, 0, nullptr, nullptr, DMODEL, 36);

  // 3. conv + silu -> u hi/lo
  conv_silu_kernel<<<NROWS*3, 256, 0, stream>>>(xz, conv_w, conv_b, u_h, u_l);

  // 4. x_proj: partials (S=6, K'=2304, T=12) then reduce -> xpo fp32 + dlow hi/lo
  gemm3<0><<<dim3(1, 32, 6), 512, 0, stream>>>(u_h, u_l, DIN, xw_h, xw_l, DIN,
      xpart, 128, (size_t)NROWS*128, nullptr, nullptr, DIN, 12);
  reduce_xproj<<<(NROWS*128)/256, 256, 0, stream>>>(xpart, xpo, dlow_h, dlow_l);

  // 5. dt_proj + bias + softplus -> delta   (M=8192, N=768, K=64, K'=192, T=6)
  gemm3<2><<<dim3(6, 32, 1), 512, 0, stream>>>(dlow_h, dlow_l, 64, dtw_h, dtw_l, 64,
      delta, DIN, 0, dt_proj_b, nullptr, 64, 6);

  // 6. chunked selective scan -> y2 hi/lo (overwrites dead xpart)
  {
    dim3 g1(DIN/256, NC, BSZ);
    scan_pass1<<<g1, 256, 0, stream>>>(delta, u_h, u_l, xpo, A_log, carryA, carryH);
    scan_mid<<<(BSZ*DIN*NST)/256, 256, 0, stream>>>(carryA, carryH);
    scan_pass2<<<g1, 256, 0, stream>>>(delta, u_h, u_l, xpo, xz, A_log, D_param,
                                       carryH, y2_h, y2_l);
  }

  // 7. out_proj + residual -> d_out   (M=8192, N=384, K=768, K'=2304, T=72)
  gemm3<3><<<dim3(3, 32, 1), 512, 0, stream>>>(y2_h, y2_l, DIN, ow_h, ow_l, DIN,
      (float*)d_out, DMODEL, 0, nullptr, x, DIN, 72);
}

// Round 6
// 276.121 us; speedup vs baseline: 1.2006x; 1.2006x over previous
//
#include <hip/hip_runtime.h>
#include <math.h>

#define DMODEL 384
#define DIN 768
#define NST 16
#define DTR 48
#define BSZ 8
#define LSEQ 1024
#define NROWS (BSZ*LSEQ)      // 8192
#define XPO_W (DTR + 2*NST)   // 80
#define CL 64                 // chunk length for scan
#define NC (LSEQ/CL)          // 16 chunks

typedef __attribute__((ext_vector_type(8))) short bf16x8;
typedef __attribute__((ext_vector_type(4))) float f32x4;

__device__ __forceinline__ unsigned short f2bf(float x) {
  unsigned int u = __float_as_uint(x);
  unsigned int r = u + 0x7fffu + ((u >> 16) & 1u);
  return (unsigned short)(r >> 16);
}
__device__ __forceinline__ float bf2f(unsigned short h) {
  return __uint_as_float(((unsigned int)h) << 16);
}

__device__ __forceinline__ void gll16(const void* g, void* l) {
  __builtin_amdgcn_global_load_lds(
      (const __attribute__((address_space(1))) void*)g,
      (__attribute__((address_space(3))) void*)l, 16, 0, 0);
}

// ---------------- LayerNorm: 4 rows per 256-thread block, emits hi/lo bf16 ----------------
__global__ __launch_bounds__(256) void ln_kernel(const float* __restrict__ x,
    const float* __restrict__ g, const float* __restrict__ b,
    unsigned short* __restrict__ xh, unsigned short* __restrict__ xl) {
  int row = blockIdx.x * 4 + (threadIdx.x >> 6);
  int lane = threadIdx.x & 63;
  const float* xr = x + (size_t)row * DMODEL;
  float v[6];
  float s = 0.f, ss = 0.f;
#pragma unroll
  for (int i = 0; i < 6; ++i) { v[i] = xr[lane + i*64]; s += v[i]; ss += v[i]*v[i]; }
#pragma unroll
  for (int off = 32; off; off >>= 1) { s += __shfl_xor(s, off); ss += __shfl_xor(ss, off); }
  float mu = s * (1.f / DMODEL);
  float var = ss * (1.f / DMODEL) - mu * mu;
  float inv = rsqrtf(var + 1e-5f);
#pragma unroll
  for (int i = 0; i < 6; ++i) {
    int c = lane + i*64;
    float o = (v[i] - mu) * inv * g[c] + b[c];
    unsigned short hv = f2bf(o);
    xh[(size_t)row*DMODEL + c] = hv;
    xl[(size_t)row*DMODEL + c] = f2bf(o - bf2f(hv));
  }
}

// ---------------- single fused weight split+pad kernel ----------------
__device__ __forceinline__ void split_one(const float* src, int ldsrc, int R, int C,
    unsigned short* dh, unsigned short* dl, int Cpad, int i) {
  int r = i / Cpad, c = i - r * Cpad;
  float v = (r < R && c < C) ? src[(size_t)r*ldsrc + c] : 0.f;
  unsigned short hv = f2bf(v);
  dh[i] = hv;
  dl[i] = f2bf(v - bf2f(hv));
}
#define N_INW (1536*384)
#define N_XW  (128*768)
#define N_DTW (768*64)
#define N_OW  (384*768)
__global__ __launch_bounds__(256) void split_weights(
    const float* __restrict__ inw, const float* __restrict__ xw,
    const float* __restrict__ dtw, const float* __restrict__ ow,
    unsigned short* inw_h, unsigned short* inw_l,
    unsigned short* xw_h, unsigned short* xw_l,
    unsigned short* dtw_h, unsigned short* dtw_l,
    unsigned short* ow_h, unsigned short* ow_l) {
  int i = blockIdx.x * 256 + threadIdx.x;
  if (i < N_INW) { split_one(inw, 384, 1536, 384, inw_h, inw_l, 384, i); return; }
  i -= N_INW;
  if (i < N_XW)  { split_one(xw, 768, 80, 768, xw_h, xw_l, 768, i); return; }
  i -= N_XW;
  if (i < N_DTW) { split_one(dtw, 48, 768, 48, dtw_h, dtw_l, 64, i); return; }
  i -= N_DTW;
  if (i < N_OW)  { split_one(ow, 768, 384, 768, ow_h, ow_l, 768, i); return; }
}

// ---------------- split-bf16 MFMA GEMM, 3-buffer counted-vmcnt pipeline ----------------
// C[M,N] = (Ah+Al)[M,K] * (Bh+Bl)[N,K]^T via 3 MFMA terms per k-step.
// BM=128, BN=128, BK=32, 512 threads = 8 waves (2m x 4n), wave tile 64x32.
// Per k-step: stage all 4 arrays for step t+2 (4 gll16/thread), vmcnt(4) counted wait.
// grid.z = split-K slices of T k-steps each, partials at C + z*strideS.
// EPI: 0 plain, 2 bias+softplus, 3 residual add
template<int EPI>
__global__ __launch_bounds__(512, 2) void gemm4(
    const unsigned short* __restrict__ Ah, const unsigned short* __restrict__ Al, int lda,
    const unsigned short* __restrict__ Bh, const unsigned short* __restrict__ Bl, int ldb,
    float* __restrict__ C, int ldc, size_t strideS,
    const float* __restrict__ bias, const float* __restrict__ res,
    int T) {
  // 3 buffers x [Ah,Al,Bh,Bl] x 512 cells x 16B = 96 KB -> 1 block/CU, 8 waves
  __shared__ unsigned short lds[3][4][4096];
  int tid = threadIdx.x;
  int lane = tid & 63, wid = tid >> 6;
  int wm = wid >> 2, wn = wid & 3;

  // bijective XCD swizzle over (x,y); all grids have nwg % 8 == 0
  unsigned nwg = gridDim.x * gridDim.y;
  unsigned bid = blockIdx.y * gridDim.x + blockIdx.x;
  unsigned cpx = nwg >> 3;
  unsigned sw = (bid & 7) * cpx + (bid >> 3);
  unsigned bx = sw % gridDim.x, by = sw / gridDim.x;
  int m0 = by * 128, n0 = bx * 128;
  C += (size_t)blockIdx.z * strideS;

  // staging geometry: array cell = tid; row = tid&127, kg = tid>>7 (k-subgroup of 8)
  int srow = tid & 127, skg = tid >> 7;
  size_t ga = (size_t)(m0 + srow) * lda + skg * 8 + (size_t)blockIdx.z * T * 32;
  size_t gb = (size_t)(n0 + srow) * ldb + skg * 8 + (size_t)blockIdx.z * T * 32;
  int dst = tid * 8;   // ushort offset; wave-linear (base + lane*16B)

#define STAGE(bf, ko) do { \
    gll16(Ah + ga + (ko), &lds[bf][0][dst]); \
    gll16(Al + ga + (ko), &lds[bf][1][dst]); \
    gll16(Bh + gb + (ko), &lds[bf][2][dst]); \
    gll16(Bl + gb + (ko), &lds[bf][3][dst]); \
  } while (0)

  f32x4 acc[4][2];
#pragma unroll
  for (int i = 0; i < 4; ++i)
#pragma unroll
    for (int j = 0; j < 2; ++j) acc[i][j] = (f32x4){0.f, 0.f, 0.f, 0.f};

  int kgl = lane >> 4, rl = lane & 15;
  int abase = (kgl*128 + wm*64 + rl) * 8;   // + mi*128
  int bbase = (kgl*128 + wn*32 + rl) * 8;   // + ni*128

  STAGE(0, 0);
  if (T > 1) STAGE(1, 32);

  int cur = 0;
  for (int t = 0; t < T; ++t) {
    if (t == T - 1) asm volatile("s_waitcnt vmcnt(0)" ::: "memory");
    else            asm volatile("s_waitcnt vmcnt(4)" ::: "memory");
    __builtin_amdgcn_s_barrier();
    if (t + 2 < T) {
      int nb = cur + 2; if (nb >= 3) nb -= 3;
      STAGE(nb, (t + 2) * 32);
    }
    bf16x8 ah[4], al[4], bh[2], bl[2];
#pragma unroll
    for (int mi = 0; mi < 4; ++mi) {
      ah[mi] = *reinterpret_cast<const bf16x8*>(&lds[cur][0][abase + mi*128]);
      al[mi] = *reinterpret_cast<const bf16x8*>(&lds[cur][1][abase + mi*128]);
    }
#pragma unroll
    for (int ni = 0; ni < 2; ++ni) {
      bh[ni] = *reinterpret_cast<const bf16x8*>(&lds[cur][2][bbase + ni*128]);
      bl[ni] = *reinterpret_cast<const bf16x8*>(&lds[cur][3][bbase + ni*128]);
    }
    __builtin_amdgcn_s_setprio(1);
#pragma unroll
    for (int mi = 0; mi < 4; ++mi)
#pragma unroll
      for (int ni = 0; ni < 2; ++ni) {
        acc[mi][ni] = __builtin_amdgcn_mfma_f32_16x16x32_bf16(ah[mi], bh[ni], acc[mi][ni], 0, 0, 0);
        acc[mi][ni] = __builtin_amdgcn_mfma_f32_16x16x32_bf16(al[mi], bh[ni], acc[mi][ni], 0, 0, 0);
        acc[mi][ni] = __builtin_amdgcn_mfma_f32_16x16x32_bf16(ah[mi], bl[ni], acc[mi][ni], 0, 0, 0);
      }
    __builtin_amdgcn_s_setprio(0);
    cur = (cur == 2) ? 0 : cur + 1;
  }
#undef STAGE

  // epilogue: C/D frag layout col=lane&15, row=(lane>>4)*4+j
#pragma unroll
  for (int mi = 0; mi < 4; ++mi)
#pragma unroll
    for (int ni = 0; ni < 2; ++ni)
#pragma unroll
      for (int j = 0; j < 4; ++j) {
        int m = m0 + wm*64 + mi*16 + (lane>>4)*4 + j;
        int n = n0 + wn*32 + ni*16 + rl;
        float v = acc[mi][ni][j];
        if (EPI == 0) {
          C[(size_t)m*ldc + n] = v;
        } else if (EPI == 2) {
          v += bias[n];
          v = (v > 20.f) ? v : log1pf(__expf(v));
          C[(size_t)m*ldc + n] = v;
        } else if (EPI == 3) {
          C[(size_t)m*ldc + n] = v + res[(size_t)m*ldc + n];
        }
      }
}

// ---------------- x_proj split-K reduce: sum 4 partials -> xpo fp32 + dlow hi/lo ----------
__global__ __launch_bounds__(256) void reduce_xproj(
    const float* __restrict__ P, float* __restrict__ xpo,
    unsigned short* __restrict__ dh, unsigned short* __restrict__ dl) {
  int idx = blockIdx.x * 256 + threadIdx.x;   // NROWS*128
  int m = idx >> 7, n = idx & 127;
  float v = 0.f;
#pragma unroll
  for (int s = 0; s < 4; ++s) v += P[(size_t)s * NROWS * 128 + idx];
  if (n < XPO_W) xpo[(size_t)m * XPO_W + n] = v;
  if (n < 64) {   // cols 48..63 multiply dtw zeros -> harmless
    unsigned short hv = f2bf(v);
    dh[(size_t)m*64 + n] = hv;
    dl[(size_t)m*64 + n] = f2bf(v - bf2f(hv));
  }
}

// ---------------- causal depthwise conv (width 4) + SiLU, emits u hi/lo ----------------
__global__ __launch_bounds__(256) void conv_silu_kernel(
    const float* __restrict__ xz, const float* __restrict__ w,
    const float* __restrict__ cb,
    unsigned short* __restrict__ uh, unsigned short* __restrict__ ul) {
  int r = blockIdx.x / 3;                       // row (b*L + l)
  int d = (blockIdx.x % 3) * 256 + threadIdx.x; // channel
  int l = r & (LSEQ - 1);
  size_t idx = (size_t)r * DIN + d;
  float acc = cb[d];
#pragma unroll
  for (int j = 0; j < 4; ++j) {
    int li = l - 3 + j;
    if (li >= 0)
      acc = fmaf(xz[(size_t)(r - l + li) * (2*DIN) + d], w[d*4 + j], acc);
  }
  float s = acc / (1.f + __expf(-acc));   // silu
  unsigned short hv = f2bf(s);
  uh[idx] = hv;
  ul[idx] = f2bf(s - bf2f(hv));
}

// ---------------- chunked selective scan ----------------
__global__ __launch_bounds__(256) void scan_pass1(
    const float* __restrict__ delta,
    const unsigned short* __restrict__ uh, const unsigned short* __restrict__ ul,
    const float* __restrict__ xpo, const float* __restrict__ A_log,
    float* __restrict__ carryA, float* __restrict__ carryH) {
  int d = blockIdx.x * 256 + threadIdx.x;
  int c = blockIdx.y, b = blockIdx.z;
  float A[16];
  {
    const float4* al = reinterpret_cast<const float4*>(A_log + (size_t)d * NST);
#pragma unroll
    for (int i = 0; i < 4; ++i) {
      float4 t = al[i];
      A[4*i+0] = -__expf(t.x); A[4*i+1] = -__expf(t.y);
      A[4*i+2] = -__expf(t.z); A[4*i+3] = -__expf(t.w);
    }
  }
  float h[16], ap[16];
#pragma unroll
  for (int n = 0; n < 16; ++n) { h[n] = 0.f; ap[n] = 1.f; }
  const float* dp = delta + ((size_t)b*LSEQ + c*CL) * DIN + d;
  const unsigned short* uhp = uh + ((size_t)b*LSEQ + c*CL) * DIN + d;
  const unsigned short* ulp = ul + ((size_t)b*LSEQ + c*CL) * DIN + d;
  const float* bp = xpo   + ((size_t)b*LSEQ + c*CL) * XPO_W + DTR;
  for (int l = 0; l < CL; ++l) {
    float dv = dp[(size_t)l*DIN];
    float uv = bf2f(uhp[(size_t)l*DIN]) + bf2f(ulp[(size_t)l*DIN]);
    float du = dv * uv;
    float Bv[16];
    {
      const float4* b4 = reinterpret_cast<const float4*>(bp + (size_t)l*XPO_W);
#pragma unroll
      for (int i = 0; i < 4; ++i) {
        float4 t = b4[i];
        Bv[4*i+0] = t.x; Bv[4*i+1] = t.y; Bv[4*i+2] = t.z; Bv[4*i+3] = t.w;
      }
    }
#pragma unroll
    for (int n = 0; n < 16; ++n) {
      float a = __expf(dv * A[n]);
      ap[n] *= a;
      h[n] = fmaf(a, h[n], du * Bv[n]);
    }
  }
  size_t ci = (((size_t)b*NC + c) * DIN + d) * NST;
  float4* ca = reinterpret_cast<float4*>(carryA + ci);
  float4* ch = reinterpret_cast<float4*>(carryH + ci);
#pragma unroll
  for (int i = 0; i < 4; ++i) {
    ca[i] = make_float4(ap[4*i], ap[4*i+1], ap[4*i+2], ap[4*i+3]);
    ch[i] = make_float4(h[4*i],  h[4*i+1],  h[4*i+2],  h[4*i+3]);
  }
}

__global__ __launch_bounds__(256) void scan_mid(
    const float* __restrict__ carryA, float* __restrict__ carryH) {
  int idx = blockIdx.x * 256 + threadIdx.x;
  int b = idx / (DIN*NST);
  int rem = idx - b * DIN*NST;
  float h = 0.f;
#pragma unroll
  for (int c = 0; c < NC; ++c) {
    size_t i = ((size_t)b*NC + c) * (DIN*NST) + rem;
    float a = carryA[i];
    float e = carryH[i];
    carryH[i] = h;
    h = fmaf(a, h, e);
  }
}

__global__ __launch_bounds__(256) void scan_pass2(
    const float* __restrict__ delta,
    const unsigned short* __restrict__ uh, const unsigned short* __restrict__ ul,
    const float* __restrict__ xpo, const float* __restrict__ xz,
    const float* __restrict__ A_log, const float* __restrict__ Dp,
    const float* __restrict__ carryH,
    unsigned short* __restrict__ yh, unsigned short* __restrict__ yl) {
  int d = blockIdx.x * 256 + threadIdx.x;
  int c = blockIdx.y, b = blockIdx.z;
  float A[16];
  {
    const float4* al = reinterpret_cast<const float4*>(A_log + (size_t)d * NST);
#pragma unroll
    for (int i = 0; i < 4; ++i) {
      float4 t = al[i];
      A[4*i+0] = -__expf(t.x); A[4*i+1] = -__expf(t.y);
      A[4*i+2] = -__expf(t.z); A[4*i+3] = -__expf(t.w);
    }
  }
  float h[16];
  size_t ci = (((size_t)b*NC + c) * DIN + d) * NST;
  {
    const float4* ch = reinterpret_cast<const float4*>(carryH + ci);
#pragma unroll
    for (int i = 0; i < 4; ++i) {
      float4 t = ch[i];
      h[4*i+0] = t.x; h[4*i+1] = t.y; h[4*i+2] = t.z; h[4*i+3] = t.w;
    }
  }
  float Dd = Dp[d];
  const float* dp = delta + ((size_t)b*LSEQ + c*CL) * DIN + d;
  const unsigned short* uhp = uh + ((size_t)b*LSEQ + c*CL) * DIN + d;
  const unsigned short* ulp = ul + ((size_t)b*LSEQ + c*CL) * DIN + d;
  const float* bp = xpo   + ((size_t)b*LSEQ + c*CL) * XPO_W + DTR;
  const float* zp = xz    + ((size_t)b*LSEQ + c*CL) * (2*DIN) + DIN + d;
  size_t yi0 = ((size_t)b*LSEQ + c*CL) * DIN + d;
  for (int l = 0; l < CL; ++l) {
    float dv = dp[(size_t)l*DIN];
    float uv = bf2f(uhp[(size_t)l*DIN]) + bf2f(ulp[(size_t)l*DIN]);
    float du = dv * uv;
    float Bv[16], Cv[16];
    {
      const float4* b4 = reinterpret_cast<const float4*>(bp + (size_t)l*XPO_W);
#pragma unroll
      for (int i = 0; i < 4; ++i) {
        float4 t = b4[i];
        Bv[4*i+0] = t.x; Bv[4*i+1] = t.y; Bv[4*i+2] = t.z; Bv[4*i+3] = t.w;
        float4 tc = b4[i+4];
        Cv[4*i+0] = tc.x; Cv[4*i+1] = tc.y; Cv[4*i+2] = tc.z; Cv[4*i+3] = tc.w;
      }
    }
    float p = 0.f;
#pragma unroll
    for (int n = 0; n < 16; ++n) {
      float a = __expf(dv * A[n]);
      h[n] = fmaf(a, h[n], du * Bv[n]);
      p = fmaf(h[n], Cv[n], p);
    }
    float z = zp[(size_t)l*(2*DIN)];
    float sz = z / (1.f + __expf(-z));
    float yv = fmaf(uv, Dd, p) * sz;
    unsigned short hv = f2bf(yv);
    yh[yi0 + (size_t)l*DIN] = hv;
    yl[yi0 + (size_t)l*DIN] = f2bf(yv - bf2f(hv));
  }
}

extern "C" void kernel_launch(void* const* d_in, const int* in_sizes, int n_in,
                              void* d_out, int out_size, void* d_ws, size_t ws_size,
                              hipStream_t stream) {
  const float* x          = (const float*)d_in[0];
  const float* ln_g       = (const float*)d_in[1];
  const float* ln_b       = (const float*)d_in[2];
  const float* in_proj_w  = (const float*)d_in[3];   // (1536,384)
  const float* conv_w     = (const float*)d_in[4];   // (768,1,4)
  const float* conv_b     = (const float*)d_in[5];
  const float* x_proj_w   = (const float*)d_in[6];   // (80,768)
  const float* dt_proj_w  = (const float*)d_in[7];   // (768,48)
  const float* dt_proj_b  = (const float*)d_in[8];
  const float* A_log      = (const float*)d_in[9];   // (768,16)
  const float* D_param    = (const float*)d_in[10];
  const float* out_proj_w = (const float*)d_in[11];  // (384,768)

  char* w = (char*)d_ws;
  // region1 (12.58MB): xn hi/lo -> dlow hi/lo -> carryA/H (lifetimes disjoint)
  unsigned short* xn_h  = (unsigned short*)w;
  unsigned short* xn_l  = xn_h + (size_t)NROWS*DMODEL;
  unsigned short* dlow_h = (unsigned short*)w;
  unsigned short* dlow_l = dlow_h + (size_t)NROWS*64;
  float* carryA = (float*)w;
  float* carryH = carryA + (size_t)BSZ*NC*DIN*NST;
  char* p = w + (size_t)NROWS*DMODEL*4;               // 12.58MB
  float* xz = (float*)p;              p += (size_t)NROWS*2*DIN*4;   // 50.33MB
  unsigned short* u_h = (unsigned short*)p;
  unsigned short* u_l = u_h + (size_t)NROWS*DIN;      p += (size_t)NROWS*DIN*4; // 25.17MB
  float* xpo = (float*)p;             p += (size_t)NROWS*XPO_W*4;   // 2.62MB
  float* delta = (float*)p;           p += (size_t)NROWS*DIN*4;     // 25.17MB
  // weight splits for in_proj/x_proj live in the (not yet written) delta region
  unsigned short* inw_h = (unsigned short*)delta;
  unsigned short* inw_l = inw_h + (size_t)1536*384;
  unsigned short* xw_h  = inw_l + (size_t)1536*384;
  unsigned short* xw_l  = xw_h + (size_t)128*768;
  // y2 region doubles as x_proj split-K partials (4 x 8192 x 128 fp32 = 16.8MB) pre-scan
  unsigned short* y2_h = (unsigned short*)p;
  unsigned short* y2_l = y2_h + (size_t)NROWS*DIN;
  float* xpart = (float*)p;           p += (size_t)NROWS*DIN*4;     // 25.17MB
  unsigned short* dtw_h = (unsigned short*)p;
  unsigned short* dtw_l = dtw_h + (size_t)768*64;
  unsigned short* ow_h  = dtw_l + (size_t)768*64;
  unsigned short* ow_l  = ow_h + (size_t)384*768;

  // 0. split all weights in one launch (pads: x_proj rows 80->128, dt_proj cols 48->64)
  split_weights<<<(N_INW+N_XW+N_DTW+N_OW)/256, 256, 0, stream>>>(
      in_proj_w, x_proj_w, dt_proj_w, out_proj_w,
      inw_h, inw_l, xw_h, xw_l, dtw_h, dtw_l, ow_h, ow_l);

  // 1. LayerNorm -> xn hi/lo
  ln_kernel<<<NROWS/4, 256, 0, stream>>>(x, ln_g, ln_b, xn_h, xn_l);

  // 2. in_proj: xz = xn @ in_proj_w^T   (M=8192, N=1536, K=384, T=12)
  gemm4<0><<<dim3(12, 64, 1), 512, 0, stream>>>(xn_h, xn_l, DMODEL, inw_h, inw_l, DMODEL,
      xz, 2*DIN, 0, nullptr, nullptr, 12);

  // 3. conv + silu -> u hi/lo
  conv_silu_kernel<<<NROWS*3, 256, 0, stream>>>(xz, conv_w, conv_b, u_h, u_l);

  // 4. x_proj: split-K partials (S=4, T=6 each) then reduce -> xpo fp32 + dlow hi/lo
  gemm4<0><<<dim3(1, 64, 4), 512, 0, stream>>>(u_h, u_l, DIN, xw_h, xw_l, DIN,
      xpart, 128, (size_t)NROWS*128, nullptr, nullptr, 6);
  reduce_xproj<<<(NROWS*128)/256, 256, 0, stream>>>(xpart, xpo, dlow_h, dlow_l);

  // 5. dt_proj + bias + softplus -> delta   (M=8192, N=768, Kpad=64, T=2)
  gemm4<2><<<dim3(6, 64, 1), 512, 0, stream>>>(dlow_h, dlow_l, 64, dtw_h, dtw_l, 64,
      delta, DIN, 0, dt_proj_b, nullptr, 2);

  // 6. chunked selective scan -> y2 hi/lo (overwrites dead xpart)
  {
    dim3 g1(DIN/256, NC, BSZ);
    scan_pass1<<<g1, 256, 0, stream>>>(delta, u_h, u_l, xpo, A_log, carryA, carryH);
    scan_mid<<<(BSZ*DIN*NST)/256, 256, 0, stream>>>(carryA, carryH);
    scan_pass2<<<g1, 256, 0, stream>>>(delta, u_h, u_l, xpo, xz, A_log, D_param,
                                       carryH, y2_h, y2_l);
  }

  // 7. out_proj + residual -> d_out   (M=8192, N=384, K=768, T=24)
  gemm4<3><<<dim3(3, 64, 1), 512, 0, stream>>>(y2_h, y2_l, DIN, ow_h, ow_l, DIN,
      (float*)d_out, DMODEL, 0, nullptr, x, 24);
}